// Round 9
// baseline (144.667 us; speedup 1.0000x reference)
//
#include <hip/hip_runtime.h>

#define B_    2
#define S_    1024
#define NH_   32
#define NKV_  8
#define T_    (B_*S_)

typedef unsigned short u16;
typedef unsigned int u32;
typedef __attribute__((ext_vector_type(8))) short bf16x8;
typedef __attribute__((ext_vector_type(4))) float f32x4;
typedef __attribute__((ext_vector_type(16))) float f32x16;

__device__ __forceinline__ float bf2f(u16 u) {
    union { float f; unsigned int i; } c; c.i = ((unsigned int)u) << 16; return c.f;
}
__device__ __forceinline__ u16 f2bf(float f) {
    union { float f; unsigned int u; } c; c.f = f;
    return (u16)((c.u + 0x7FFFu + ((c.u >> 16) & 1u)) >> 16);
}
// pack two f32 -> 2xbf16 (lo in low16)
__device__ __forceinline__ u32 cvtpk(float lo, float hi) {
    u32 r;
    asm("v_cvt_pk_bf16_f32 %0, %1, %2" : "=v"(r) : "v"(lo), "v"(hi));
    return r;
}

// async global->LDS, 16B per lane; LDS dest = wave-uniform base + lane*16 (linear)
__device__ __forceinline__ void gld_lds16(const void* g, void* s) {
    __builtin_amdgcn_global_load_lds(
        (const __attribute__((address_space(1))) void*)g,
        (__attribute__((address_space(3))) void*)s,
        16, 0, 0);
}

// ------------------------------------------------------------------
// preproc1: [0,2048) hidden f32->bf16; [2048,3584) wqkv pack-transpose;
//           [3584,4608) wo transpose -> woT bf16 [2048][2048]
// ------------------------------------------------------------------
__global__ __launch_bounds__(256) void preproc1(
    const float* __restrict__ hidden, const float* __restrict__ wq,
    const float* __restrict__ wk, const float* __restrict__ wv,
    const float* __restrict__ wo,
    u16* __restrict__ hidden_bf, u16* __restrict__ wqkvT, u16* __restrict__ woT)
{
    __shared__ float t[64][65];
    const int bid = blockIdx.x, tid = threadIdx.x;
    if (bid < 2048) {
        int i = (bid * 256 + tid) * 8;
        float4 v0 = *reinterpret_cast<const float4*>(&hidden[i]);
        float4 v1 = *reinterpret_cast<const float4*>(&hidden[i + 4]);
        u16 o[8] = { f2bf(v0.x), f2bf(v0.y), f2bf(v0.z), f2bf(v0.w),
                     f2bf(v1.x), f2bf(v1.y), f2bf(v1.z), f2bf(v1.w) };
        *reinterpret_cast<uint4*>(&hidden_bf[i]) = *reinterpret_cast<uint4*>(o);
        return;
    }
    const float* src; int scol, sN, n0, k0;
    u16* dst; int dK;
    if (bid < 3584) {
        const int tt = bid - 2048;
        n0 = (tt % 48) * 64; k0 = (tt / 48) * 64;
        if (n0 < 2048)      { src = wq; scol = n0;        sN = 2048; }
        else if (n0 < 2560) { src = wk; scol = n0 - 2048; sN = 512;  }
        else                { src = wv; scol = n0 - 2560; sN = 512;  }
        dst = wqkvT; dK = 2048;
    } else {
        const int tt = bid - 3584;
        n0 = (tt % 32) * 64; k0 = (tt / 32) * 64;
        src = wo; scol = n0; sN = 2048;
        dst = woT; dK = 2048;
    }
    #pragma unroll
    for (int i = 0; i < 16; ++i) {
        int e = i * 256 + tid, r = e >> 6, c = e & 63;
        t[r][c] = src[(size_t)(k0 + r) * sN + scol + c];
    }
    __syncthreads();
    #pragma unroll
    for (int i = 0; i < 16; ++i) {
        int e = i * 256 + tid, rr = e >> 6, cc = e & 63;
        dst[(size_t)(n0 + rr) * dK + k0 + cc] = f2bf(t[cc][rr]);
    }
}

// ------------------------------------------------------------------
// bf16 MFMA GEMM, B^T input. C[M,N] = A[M,K] @ Bt[N,K]^T
// 128x64 tile, BK=64, 4 waves (2x2), wave-tile 64x32, T2 XOR-swizzled
// LDS, double-buffered counted-vmcnt staging, T1 XCD-chunked 1D grid.
// ------------------------------------------------------------------
template<bool OUT_BF16>
__global__ __launch_bounds__(256) void gemm_bt(
    const u16* __restrict__ A, const u16* __restrict__ Bt,
    void* __restrict__ Cv, int M, int N, int K)
{
    __shared__ u16 As[2][128 * 64];
    __shared__ u16 Bs[2][64 * 64];
    const int MB = M >> 7;
    const int cpx = gridDim.x >> 3;
    const int L = (blockIdx.x & 7) * cpx + (blockIdx.x >> 3);  // XCD-chunked
    const int bm = (L % MB) * 128, bn = (L / MB) * 64;
    const int tid = threadIdx.x;
    const int w = tid >> 6, lane = tid & 63;
    const int wr = w >> 1, wc = w & 1;
    const int l15 = lane & 15, lg = lane >> 4;
    const int srow = lane >> 3;                       // 0..7
    const int scolsw = (lane & 7) ^ srow;             // swizzled source 16B-chunk

    f32x4 acc[4][2] = {};
    const int nk = K >> 6;

#define GSTAGE(ks, bb) do {                                                    \
    const int kofs = (ks) * 64;                                                \
    _Pragma("unroll")                                                          \
    for (int i_ = 0; i_ < 4; ++i_) {                                           \
        int chunk_ = w * 4 + i_;                                               \
        int row_ = chunk_ * 8 + srow;                                          \
        gld_lds16(&A[(size_t)(bm + row_) * K + kofs + scolsw * 8],             \
                  &As[bb][chunk_ * 512]);                                      \
    }                                                                          \
    _Pragma("unroll")                                                          \
    for (int j_ = 0; j_ < 2; ++j_) {                                           \
        int chunk_ = w * 2 + j_;                                               \
        int row_ = chunk_ * 8 + srow;                                          \
        gld_lds16(&Bt[(size_t)(bn + row_) * K + kofs + scolsw * 8],            \
                  &Bs[bb][chunk_ * 512]);                                      \
    } } while (0)

    GSTAGE(0, 0);
    for (int ks = 0; ks < nk; ++ks) {
        const int cur = ks & 1;
        if (ks + 1 < nk) {
            GSTAGE(ks + 1, cur ^ 1);
            asm volatile("s_waitcnt vmcnt(6)" ::: "memory");
        } else {
            asm volatile("s_waitcnt vmcnt(0)" ::: "memory");
        }
        __builtin_amdgcn_sched_barrier(0);
        __builtin_amdgcn_s_barrier();
        __builtin_amdgcn_sched_barrier(0);

        #pragma unroll
        for (int kk = 0; kk < 2; ++kk) {
            const int phys = ((kk * 4 + lg) ^ (l15 & 7)) * 8;
            bf16x8 a[4], b[2];
            #pragma unroll
            for (int m = 0; m < 4; ++m)
                a[m] = *reinterpret_cast<const bf16x8*>(
                    &As[cur][(wr * 64 + m * 16 + l15) * 64 + phys]);
            #pragma unroll
            for (int n = 0; n < 2; ++n)
                b[n] = *reinterpret_cast<const bf16x8*>(
                    &Bs[cur][(wc * 32 + n * 16 + l15) * 64 + phys]);
            #pragma unroll
            for (int m = 0; m < 4; ++m)
                #pragma unroll
                for (int n = 0; n < 2; ++n)
                    acc[m][n] = __builtin_amdgcn_mfma_f32_16x16x32_bf16(
                        a[m], b[n], acc[m][n], 0, 0, 0);
        }
        __builtin_amdgcn_sched_barrier(0);
        __builtin_amdgcn_s_barrier();   // protect buffer reuse next iter
    }
#undef GSTAGE

    const int orow0 = bm + wr * 64, ocol0 = bn + wc * 32;
    #pragma unroll
    for (int m = 0; m < 4; ++m)
        #pragma unroll
        for (int n = 0; n < 2; ++n)
            #pragma unroll
            for (int r = 0; r < 4; ++r) {
                int row = orow0 + m * 16 + lg * 4 + r;
                int col = ocol0 + n * 16 + l15;
                float v = acc[m][n][r];
                if (OUT_BF16)
                    ((u16*)Cv)[(size_t)row * N + col] = f2bf(v);
                else
                    ((float*)Cv)[(size_t)row * N + col] = v;
            }
}

// ------------------------------------------------------------------
// Merged RMSNorm+RoPE (blocks [0,2048), token per block) and
// V transpose (blocks [2048,2304)) -> vT [(b*8+kvh)*64+d][1024]
// ------------------------------------------------------------------
template<int DIM>
__device__ __forceinline__ void rms_rope_row(
    u16* base, const float* __restrict__ w,
    const float* __restrict__ cs, const float* __restrict__ sn,
    float* row, float* red, int tid)
{
    float ss = 0.f;
    for (int i0 = tid * 8; i0 < DIM; i0 += 2048) {
        uint4 u = *reinterpret_cast<const uint4*>(&base[i0]);
        const u16* us = reinterpret_cast<const u16*>(&u);
        #pragma unroll
        for (int j = 0; j < 8; ++j) { float f = bf2f(us[j]); row[i0 + j] = f; ss += f * f; }
    }
    #pragma unroll
    for (int off = 1; off < 64; off <<= 1) ss += __shfl_xor(ss, off);
    if ((tid & 63) == 0) red[tid >> 6] = ss;
    __syncthreads();
    const float rstd = rsqrtf((red[0] + red[1] + red[2] + red[3]) * (1.0f / DIM) + 1e-6f);

    for (int i0 = tid * 8; i0 < DIM; i0 += 2048) {
        u16 o[8];
        #pragma unroll
        for (int j = 0; j < 8; ++j) {
            int i = i0 + j, dh = i & 63, bb = i & ~63;
            int oi = (dh < 32) ? bb + dh + 32 : bb + dh - 32;
            float y     = row[i]  * rstd * w[i];
            float other = row[oi] * rstd * w[oi];
            if (dh < 32) other = -other;
            o[j] = f2bf(y * cs[dh] + other * sn[dh]);
        }
        *reinterpret_cast<uint4*>(&base[i0]) = *reinterpret_cast<uint4*>(o);
    }
}

__global__ __launch_bounds__(256) void rmsnorm_rope_vt(
    u16* __restrict__ x, const float* __restrict__ qnw, const float* __restrict__ knw,
    const float* __restrict__ cosb, const float* __restrict__ sinb,
    u16* __restrict__ vT)
{
    __shared__ float smem[2304];          // 9216 B, aliased
    const int bid = blockIdx.x, tid = threadIdx.x;
    if (bid < 2048) {
        const int t = bid;
        float* row = smem;
        float* red = smem + 2048;
        const float* cs = cosb + (size_t)t * 64;
        const float* sn = sinb + (size_t)t * 64;
        rms_rope_row<2048>(x + (size_t)t * 3072,        qnw, cs, sn, row, red, tid);
        __syncthreads();
        rms_rope_row<512 >(x + (size_t)t * 3072 + 2048, knw, cs, sn, row, red, tid);
        return;
    }
    // V transpose
    u16 (*tu)[72] = reinterpret_cast<u16(*)[72]>(smem);
    const int bid2 = bid - 2048;
    const int hd = bid2 % 16;              // b*8 + kvh
    const int s0 = (bid2 / 16) * 64;
    const int b = hd >> 3, kvh = hd & 7;
    #pragma unroll
    for (int i = 0; i < 2; ++i) {
        int chunk = i * 256 + tid;
        int r = chunk >> 3, c8 = (chunk & 7) * 8;
        uint4 u = *reinterpret_cast<const uint4*>(
            &x[(size_t)(b * 1024 + s0 + r) * 3072 + 2560 + kvh * 64 + c8]);
        *reinterpret_cast<uint4*>(&tu[r][c8]) = u;
    }
    __syncthreads();
    #pragma unroll
    for (int i = 0; i < 2; ++i) {
        int chunk = i * 256 + tid;
        int d = chunk >> 3, c8 = (chunk & 7) * 8;
        u16 o[8];
        #pragma unroll
        for (int j = 0; j < 8; ++j) o[j] = tu[c8 + j][d];
        *reinterpret_cast<uint4*>(&vT[((size_t)(hd * 64 + d)) * 1024 + s0 + c8])
            = *reinterpret_cast<uint4*>(o);
    }
}

// ------------------------------------------------------------------
// MFMA flash attention v8: composes the session's three proven pieces:
//  - r4's both-swapped 32x32x16 structure: QK^T = mfma(K,Q), PV =
//    mfma(V^T,P); q fully lane-local; P built IN REGISTERS via
//    cvt_pk + one cross-half shfl (no Ps LDS, no lgkm round-trip).
//  - r6's causal pair-tiling: 64-row strips p & 15-p, uniform 17 steps.
//  - r8's max-free softmax (RMSNorm bounds |S|): no running max, no
//    rescale; per-lane l partials, completed in the epilogue.
// Block = 2 waves (128 thr), wave w owns q-rows strip*64+w*32..+32.
// K/V double-buffered in LDS (32KB), counted vmcnt(8), XCD-chunked.
// ------------------------------------------------------------------
__global__ __launch_bounds__(128) void attn_pair32(
    const u16* __restrict__ qkv,  // [2048][3072]
    const u16* __restrict__ vT,   // [16*64][1024]  (rows=d, cols=seq)
    u16* __restrict__ ob)         // [2048][2048]
{
    __shared__ u16 Ks[2][64 * 64];   // [key][d], XOR-swizzled 16B chunks
    __shared__ u16 Vs[2][64 * 64];   // [d][key], XOR-swizzled 16B chunks

    const int bid = blockIdx.x;
    const int L   = (bid & 7) * 64 + (bid >> 3);   // XCD-chunked, bijective
    const int g5  = L >> 5;                        // b*8 + kvh
    const int rem = L & 31;
    const int ha  = rem & 3;
    const int p   = rem >> 2;                      // pair index 0..7
    const int b = g5 >> 3, kvh = g5 & 7;
    const int h = kvh * 4 + ha;
    const int spA = p, spB = 15 - p;               // 64-row strips
    const int tilesA = p + 1;

    const int tid = threadIdx.x, w = tid >> 6, lane = tid & 63;
    const int l31 = lane & 31, hi = lane >> 5;
    const int srow = lane >> 3;
    const int scolsw = (lane & 7) ^ srow;

    const int qA_seq = spA * 64 + w * 32 + l31;
    const int qB_seq = spB * 64 + w * 32 + l31;

    // Q fragments (B-operand of 32x32x16): Q[q=l31][s*16+hi*8 ..+8]
    bf16x8 qfA[4], qfB[4];
    {
        const u16* qra = qkv + (size_t)(b * 1024 + qA_seq) * 3072 + h * 64;
        const u16* qrb = qkv + (size_t)(b * 1024 + qB_seq) * 3072 + h * 64;
        #pragma unroll
        for (int s = 0; s < 4; ++s) {
            qfA[s] = *reinterpret_cast<const bf16x8*>(&qra[s * 16 + hi * 8]);
            qfB[s] = *reinterpret_cast<const bf16x8*>(&qrb[s * 16 + hi * 8]);
        }
    }
    asm volatile("s_waitcnt vmcnt(0)" ::: "memory");   // clean vmcnt for pipeline

    float lrA = 0.f, lrB = 0.f;          // per-lane partial row sums
    f32x16 oaccA[2] = {}, oaccB[2] = {}; // O[d][q=l31], dg -> d 0..31/32..63

    const u16* kbase = qkv + 2048 + kvh * 64;
    const u16* vbase = vT + (size_t)(g5 * 64) * 1024;

// 2 waves stage 64x64 K + 64x64 V: 8 chunks of 8 rows each; wave w does 4.
#define ASTAGE(kt, bb) do {                                                    \
    _Pragma("unroll")                                                          \
    for (int i_ = 0; i_ < 4; ++i_) {                                           \
        int chunk_ = w * 4 + i_;                                               \
        int row_ = chunk_ * 8 + srow;                                          \
        gld_lds16(&kbase[(size_t)(b * 1024 + (kt) * 64 + row_) * 3072          \
                         + scolsw * 8], &Ks[bb][chunk_ * 512]);                \
        gld_lds16(&vbase[(size_t)row_ * 1024 + (kt) * 64 + scolsw * 8],        \
                  &Vs[bb][chunk_ * 512]);                                      \
    } } while (0)

    // one tile-step: both-swapped 32x32, max-free, P in registers
    auto step = [&](int kt, int cur, const bf16x8 (&qf)[4],
                    float& lr, f32x16 (&oacc)[2], int q_seq, bool dz) {
        // QK^T (swapped): D[key][q]
        f32x16 sacc[2] = {};
        #pragma unroll
        for (int gg = 0; gg < 2; ++gg)
            #pragma unroll
            for (int s = 0; s < 4; ++s) {
                const int phys = ((s * 2 + hi) ^ (l31 & 7)) * 8;
                bf16x8 kf = *reinterpret_cast<const bf16x8*>(
                    &Ks[cur][(gg * 32 + l31) * 64 + phys]);
                sacc[gg] = __builtin_amdgcn_mfma_f32_32x32x16_bf16(
                    kf, qf[s], sacc[gg], 0, 0, 0);
            }

        // max-free softmax (base-2); masked -> exp2(-huge) = 0
        const float SC = 0.18033688f;      // 0.125 * log2(e)
        float pv[2][16];
        #pragma unroll
        for (int gg = 0; gg < 2; ++gg)
            #pragma unroll
            for (int r = 0; r < 16; ++r) {
                float v = sacc[gg][r] * SC;
                if (dz) {
                    const int key = kt * 64 + gg * 32
                                  + (r & 3) + 8 * (r >> 2) + 4 * hi;
                    if (key > q_seq) v = -1e30f;
                }
                float e = exp2f(v);
                pv[gg][r] = e;
                lr += e;                   // per-lane partial (half the keys;
            }                              //  completed via shfl in epilogue)

        // build P fragments (B-operand) in registers — r4-verified
        bf16x8 pfrag[4];
        #pragma unroll
        for (int gg = 0; gg < 2; ++gg)
            #pragma unroll
            for (int hh = 0; hh < 2; ++hh) {
                const int r0 = hh * 8;
                u32 Aw = cvtpk(pv[gg][r0+0], pv[gg][r0+1]);
                u32 Bw = cvtpk(pv[gg][r0+2], pv[gg][r0+3]);
                u32 Cw = cvtpk(pv[gg][r0+4], pv[gg][r0+5]);
                u32 Dw = cvtpk(pv[gg][r0+6], pv[gg][r0+7]);
                u32 Ax = __shfl_xor(Aw, 32), Bx = __shfl_xor(Bw, 32);
                u32 Cx = __shfl_xor(Cw, 32), Dx = __shfl_xor(Dw, 32);
                u32 ww[4];
                ww[0] = hi ? Cx : Aw;
                ww[1] = hi ? Dx : Bw;
                ww[2] = hi ? Cw : Ax;
                ww[3] = hi ? Dw : Bx;
                pfrag[gg * 2 + hh] = *reinterpret_cast<const bf16x8*>(ww);
            }

        // PV (swapped): O[d][q] += V^T[d][key] * P[key][q]
        #pragma unroll
        for (int dg = 0; dg < 2; ++dg)
            #pragma unroll
            for (int s = 0; s < 4; ++s) {
                const int phys = ((s * 2 + hi) ^ (l31 & 7)) * 8;
                bf16x8 vf = *reinterpret_cast<const bf16x8*>(
                    &Vs[cur][(dg * 32 + l31) * 64 + phys]);
                oacc[dg] = __builtin_amdgcn_mfma_f32_32x32x16_bf16(
                    vf, pfrag[s], oacc[dg], 0, 0, 0);
            }
    };

    // unified 17-step schedule: s < tilesA -> strip A (kt=s), else B
    ASTAGE(0, 0);
    for (int s = 0; s <= 16; ++s) {
        const int cur = s & 1;
        if (s < 16) {
            const int sn = s + 1;
            const int ktn = (sn < tilesA) ? sn : (sn - tilesA);
            ASTAGE(ktn, cur ^ 1);
            asm volatile("s_waitcnt vmcnt(8)" ::: "memory");
        } else {
            asm volatile("s_waitcnt vmcnt(0)" ::: "memory");
        }
        __builtin_amdgcn_sched_barrier(0);
        __builtin_amdgcn_s_barrier();
        __builtin_amdgcn_sched_barrier(0);

        if (s < tilesA)
            step(s,          cur, qfA, lrA, oaccA, qA_seq, s == tilesA - 1);
        else
            step(s - tilesA, cur, qfB, lrB, oaccB, qB_seq, s == 16);

        __builtin_amdgcn_sched_barrier(0);
        __builtin_amdgcn_s_barrier();    // all reads of cur done before reuse
    }
#undef ASTAGE

    // epilogues: complete l across the two lane-halves, then normalize.
    // lane owns q=q_seq; d = dg*32 + 8*rq + 4*hi + j
    #pragma unroll
    for (int tt = 0; tt < 2; ++tt) {
        const int q_seq = tt ? qB_seq : qA_seq;
        float lr = tt ? lrB : lrA;
        const float lsum = lr + __shfl_xor(lr, 32);
        const float linv = 1.f / lsum;
        f32x16* oacc = tt ? oaccB : oaccA;
        u16* orow = ob + (size_t)(b * 1024 + q_seq) * 2048 + h * 64;
        #pragma unroll
        for (int dg = 0; dg < 2; ++dg)
            #pragma unroll
            for (int rq = 0; rq < 4; ++rq) {
                u16 o4[4];
                #pragma unroll
                for (int j = 0; j < 4; ++j)
                    o4[j] = f2bf(oacc[dg][rq * 4 + j] * linv);
                *reinterpret_cast<uint2*>(&orow[dg * 32 + 8 * rq + 4 * hi])
                    = *reinterpret_cast<const uint2*>(o4);
            }
    }
}

// ------------------------------------------------------------------
extern "C" void kernel_launch(void* const* d_in, const int* in_sizes, int n_in,
                              void* d_out, int out_size, void* d_ws, size_t ws_size,
                              hipStream_t stream)
{
    const float* hidden = (const float*)d_in[0];
    const float* cosb   = (const float*)d_in[1];
    const float* sinb   = (const float*)d_in[2];
    // d_in[3] = attention_mask (pure causal; handled analytically)
    const float* wq     = (const float*)d_in[4];
    const float* wk     = (const float*)d_in[5];
    const float* wv     = (const float*)d_in[6];
    const float* wo     = (const float*)d_in[7];
    const float* qnw    = (const float*)d_in[8];
    const float* knw    = (const float*)d_in[9];
    float* out = (float*)d_out;

    char* ws = (char*)d_ws;
    u16* hidden_bf = (u16*)ws;                          // [0,8M)
    u16* wqkvT     = (u16*)(ws + ((size_t)8  << 20));   // [8,20M) -> later attn_bf
    u16* attn_bf   = (u16*)(ws + ((size_t)8  << 20));
    u16* qkv_bf    = (u16*)(ws + ((size_t)20 << 20));   // [20,32M)
    u16* v_bfT     = (u16*)(ws + ((size_t)32 << 20));   // [32,34M)
    u16* woT       = (u16*)(ws + ((size_t)34 << 20));   // [34,42M)

    // hidden -> bf16, wq|wk|wv pack-transpose, wo transpose
    preproc1<<<4608, 256, 0, stream>>>(hidden, wq, wk, wv, wo,
                                       hidden_bf, wqkvT, woT);

    // fused QKV projection: [2048,2048] @ [2048,3072] -> bf16 [2048,3072]
    gemm_bt<true><<<768, 256, 0, stream>>>(hidden_bf, wqkvT, qkv_bf,
                                           2048, 3072, 2048);

    // RMSNorm + RoPE for Q and K (in place) + V transpose
    rmsnorm_rope_vt<<<2304, 256, 0, stream>>>(qkv_bf, qnw, knw, cosb, sinb, v_bfT);

    // attention -> attn_bf (aliases wqkvT region, free after QKV GEMM)
    attn_pair32<<<512, 128, 0, stream>>>(qkv_bf, v_bfT, attn_bf);

    // output projection: [2048,2048] @ woT^T -> fp32 out
    gemm_bt<false><<<512, 256, 0, stream>>>(attn_bf, woT, out,
                                            2048, 2048, 2048);
}

// Round 10
// 144.315 us; speedup vs baseline: 1.0024x; 1.0024x over previous
//
#include <hip/hip_runtime.h>

#define B_    2
#define S_    1024
#define NH_   32
#define NKV_  8
#define T_    (B_*S_)

typedef unsigned short u16;
typedef unsigned int u32;
typedef __attribute__((ext_vector_type(8))) short bf16x8;
typedef __attribute__((ext_vector_type(4))) float f32x4;
typedef __attribute__((ext_vector_type(16))) float f32x16;

__device__ __forceinline__ float bf2f(u16 u) {
    union { float f; unsigned int i; } c; c.i = ((unsigned int)u) << 16; return c.f;
}
__device__ __forceinline__ u16 f2bf(float f) {
    union { float f; unsigned int u; } c; c.f = f;
    return (u16)((c.u + 0x7FFFu + ((c.u >> 16) & 1u)) >> 16);
}
// pack two f32 -> 2xbf16 (lo in low16)
__device__ __forceinline__ u32 cvtpk(float lo, float hi) {
    u32 r;
    asm("v_cvt_pk_bf16_f32 %0, %1, %2" : "=v"(r) : "v"(lo), "v"(hi));
    return r;
}

// async global->LDS, 16B per lane; LDS dest = wave-uniform base + lane*16 (linear)
__device__ __forceinline__ void gld_lds16(const void* g, void* s) {
    __builtin_amdgcn_global_load_lds(
        (const __attribute__((address_space(1))) void*)g,
        (__attribute__((address_space(3))) void*)s,
        16, 0, 0);
}

// ------------------------------------------------------------------
// preproc1: [0,2048) hidden f32->bf16; [2048,3584) wqkv pack-transpose;
//           [3584,4608) wo transpose -> woT bf16 [2048][2048]
// ------------------------------------------------------------------
__global__ __launch_bounds__(256) void preproc1(
    const float* __restrict__ hidden, const float* __restrict__ wq,
    const float* __restrict__ wk, const float* __restrict__ wv,
    const float* __restrict__ wo,
    u16* __restrict__ hidden_bf, u16* __restrict__ wqkvT, u16* __restrict__ woT)
{
    __shared__ float t[64][65];
    const int bid = blockIdx.x, tid = threadIdx.x;
    if (bid < 2048) {
        int i = (bid * 256 + tid) * 8;
        float4 v0 = *reinterpret_cast<const float4*>(&hidden[i]);
        float4 v1 = *reinterpret_cast<const float4*>(&hidden[i + 4]);
        u16 o[8] = { f2bf(v0.x), f2bf(v0.y), f2bf(v0.z), f2bf(v0.w),
                     f2bf(v1.x), f2bf(v1.y), f2bf(v1.z), f2bf(v1.w) };
        *reinterpret_cast<uint4*>(&hidden_bf[i]) = *reinterpret_cast<uint4*>(o);
        return;
    }
    const float* src; int scol, sN, n0, k0;
    u16* dst; int dK;
    if (bid < 3584) {
        const int tt = bid - 2048;
        n0 = (tt % 48) * 64; k0 = (tt / 48) * 64;
        if (n0 < 2048)      { src = wq; scol = n0;        sN = 2048; }
        else if (n0 < 2560) { src = wk; scol = n0 - 2048; sN = 512;  }
        else                { src = wv; scol = n0 - 2560; sN = 512;  }
        dst = wqkvT; dK = 2048;
    } else {
        const int tt = bid - 3584;
        n0 = (tt % 32) * 64; k0 = (tt / 32) * 64;
        src = wo; scol = n0; sN = 2048;
        dst = woT; dK = 2048;
    }
    #pragma unroll
    for (int i = 0; i < 16; ++i) {
        int e = i * 256 + tid, r = e >> 6, c = e & 63;
        t[r][c] = src[(size_t)(k0 + r) * sN + scol + c];
    }
    __syncthreads();
    #pragma unroll
    for (int i = 0; i < 16; ++i) {
        int e = i * 256 + tid, rr = e >> 6, cc = e & 63;
        dst[(size_t)(n0 + rr) * dK + k0 + cc] = f2bf(t[cc][rr]);
    }
}

// ------------------------------------------------------------------
// bf16 MFMA GEMM, B^T input. C[M,N] = A[M,K] @ Bt[N,K]^T
// 128x64 tile, BK=64, 4 waves (2x2), wave-tile 64x32, T2 XOR-swizzled
// LDS, double-buffered counted-vmcnt staging, T1 XCD-chunked 1D grid.
// ------------------------------------------------------------------
template<bool OUT_BF16>
__global__ __launch_bounds__(256) void gemm_bt(
    const u16* __restrict__ A, const u16* __restrict__ Bt,
    void* __restrict__ Cv, int M, int N, int K)
{
    __shared__ u16 As[2][128 * 64];
    __shared__ u16 Bs[2][64 * 64];
    const int MB = M >> 7;
    const int cpx = gridDim.x >> 3;
    const int L = (blockIdx.x & 7) * cpx + (blockIdx.x >> 3);  // XCD-chunked
    const int bm = (L % MB) * 128, bn = (L / MB) * 64;
    const int tid = threadIdx.x;
    const int w = tid >> 6, lane = tid & 63;
    const int wr = w >> 1, wc = w & 1;
    const int l15 = lane & 15, lg = lane >> 4;
    const int srow = lane >> 3;                       // 0..7
    const int scolsw = (lane & 7) ^ srow;             // swizzled source 16B-chunk

    f32x4 acc[4][2] = {};
    const int nk = K >> 6;

#define GSTAGE(ks, bb) do {                                                    \
    const int kofs = (ks) * 64;                                                \
    _Pragma("unroll")                                                          \
    for (int i_ = 0; i_ < 4; ++i_) {                                           \
        int chunk_ = w * 4 + i_;                                               \
        int row_ = chunk_ * 8 + srow;                                          \
        gld_lds16(&A[(size_t)(bm + row_) * K + kofs + scolsw * 8],             \
                  &As[bb][chunk_ * 512]);                                      \
    }                                                                          \
    _Pragma("unroll")                                                          \
    for (int j_ = 0; j_ < 2; ++j_) {                                           \
        int chunk_ = w * 2 + j_;                                               \
        int row_ = chunk_ * 8 + srow;                                          \
        gld_lds16(&Bt[(size_t)(bn + row_) * K + kofs + scolsw * 8],            \
                  &Bs[bb][chunk_ * 512]);                                      \
    } } while (0)

    GSTAGE(0, 0);
    for (int ks = 0; ks < nk; ++ks) {
        const int cur = ks & 1;
        if (ks + 1 < nk) {
            GSTAGE(ks + 1, cur ^ 1);
            asm volatile("s_waitcnt vmcnt(6)" ::: "memory");
        } else {
            asm volatile("s_waitcnt vmcnt(0)" ::: "memory");
        }
        __builtin_amdgcn_sched_barrier(0);
        __builtin_amdgcn_s_barrier();
        __builtin_amdgcn_sched_barrier(0);

        #pragma unroll
        for (int kk = 0; kk < 2; ++kk) {
            const int phys = ((kk * 4 + lg) ^ (l15 & 7)) * 8;
            bf16x8 a[4], b[2];
            #pragma unroll
            for (int m = 0; m < 4; ++m)
                a[m] = *reinterpret_cast<const bf16x8*>(
                    &As[cur][(wr * 64 + m * 16 + l15) * 64 + phys]);
            #pragma unroll
            for (int n = 0; n < 2; ++n)
                b[n] = *reinterpret_cast<const bf16x8*>(
                    &Bs[cur][(wc * 32 + n * 16 + l15) * 64 + phys]);
            #pragma unroll
            for (int m = 0; m < 4; ++m)
                #pragma unroll
                for (int n = 0; n < 2; ++n)
                    acc[m][n] = __builtin_amdgcn_mfma_f32_16x16x32_bf16(
                        a[m], b[n], acc[m][n], 0, 0, 0);
        }
        __builtin_amdgcn_sched_barrier(0);
        __builtin_amdgcn_s_barrier();   // protect buffer reuse next iter
    }
#undef GSTAGE

    const int orow0 = bm + wr * 64, ocol0 = bn + wc * 32;
    #pragma unroll
    for (int m = 0; m < 4; ++m)
        #pragma unroll
        for (int n = 0; n < 2; ++n)
            #pragma unroll
            for (int r = 0; r < 4; ++r) {
                int row = orow0 + m * 16 + lg * 4 + r;
                int col = ocol0 + n * 16 + l15;
                float v = acc[m][n][r];
                if (OUT_BF16)
                    ((u16*)Cv)[(size_t)row * N + col] = f2bf(v);
                else
                    ((float*)Cv)[(size_t)row * N + col] = v;
            }
}

// ------------------------------------------------------------------
// Merged RMSNorm+RoPE (blocks [0,2048), token per block) and
// V transpose (blocks [2048,2304)) -> vT [(b*8+kvh)*64+d][1024]
// ------------------------------------------------------------------
template<int DIM>
__device__ __forceinline__ void rms_rope_row(
    u16* base, const float* __restrict__ w,
    const float* __restrict__ cs, const float* __restrict__ sn,
    float* row, float* red, int tid)
{
    float ss = 0.f;
    for (int i0 = tid * 8; i0 < DIM; i0 += 2048) {
        uint4 u = *reinterpret_cast<const uint4*>(&base[i0]);
        const u16* us = reinterpret_cast<const u16*>(&u);
        #pragma unroll
        for (int j = 0; j < 8; ++j) { float f = bf2f(us[j]); row[i0 + j] = f; ss += f * f; }
    }
    #pragma unroll
    for (int off = 1; off < 64; off <<= 1) ss += __shfl_xor(ss, off);
    if ((tid & 63) == 0) red[tid >> 6] = ss;
    __syncthreads();
    const float rstd = rsqrtf((red[0] + red[1] + red[2] + red[3]) * (1.0f / DIM) + 1e-6f);

    for (int i0 = tid * 8; i0 < DIM; i0 += 2048) {
        u16 o[8];
        #pragma unroll
        for (int j = 0; j < 8; ++j) {
            int i = i0 + j, dh = i & 63, bb = i & ~63;
            int oi = (dh < 32) ? bb + dh + 32 : bb + dh - 32;
            float y     = row[i]  * rstd * w[i];
            float other = row[oi] * rstd * w[oi];
            if (dh < 32) other = -other;
            o[j] = f2bf(y * cs[dh] + other * sn[dh]);
        }
        *reinterpret_cast<uint4*>(&base[i0]) = *reinterpret_cast<uint4*>(o);
    }
}

__global__ __launch_bounds__(256) void rmsnorm_rope_vt(
    u16* __restrict__ x, const float* __restrict__ qnw, const float* __restrict__ knw,
    const float* __restrict__ cosb, const float* __restrict__ sinb,
    u16* __restrict__ vT)
{
    __shared__ float smem[2304];          // 9216 B, aliased
    const int bid = blockIdx.x, tid = threadIdx.x;
    if (bid < 2048) {
        const int t = bid;
        float* row = smem;
        float* red = smem + 2048;
        const float* cs = cosb + (size_t)t * 64;
        const float* sn = sinb + (size_t)t * 64;
        rms_rope_row<2048>(x + (size_t)t * 3072,        qnw, cs, sn, row, red, tid);
        __syncthreads();
        rms_rope_row<512 >(x + (size_t)t * 3072 + 2048, knw, cs, sn, row, red, tid);
        return;
    }
    // V transpose
    u16 (*tu)[72] = reinterpret_cast<u16(*)[72]>(smem);
    const int bid2 = bid - 2048;
    const int hd = bid2 % 16;              // b*8 + kvh
    const int s0 = (bid2 / 16) * 64;
    const int b = hd >> 3, kvh = hd & 7;
    #pragma unroll
    for (int i = 0; i < 2; ++i) {
        int chunk = i * 256 + tid;
        int r = chunk >> 3, c8 = (chunk & 7) * 8;
        uint4 u = *reinterpret_cast<const uint4*>(
            &x[(size_t)(b * 1024 + s0 + r) * 3072 + 2560 + kvh * 64 + c8]);
        *reinterpret_cast<uint4*>(&tu[r][c8]) = u;
    }
    __syncthreads();
    #pragma unroll
    for (int i = 0; i < 2; ++i) {
        int chunk = i * 256 + tid;
        int d = chunk >> 3, c8 = (chunk & 7) * 8;
        u16 o[8];
        #pragma unroll
        for (int j = 0; j < 8; ++j) o[j] = tu[c8 + j][d];
        *reinterpret_cast<uint4*>(&vT[((size_t)(hd * 64 + d)) * 1024 + s0 + c8])
            = *reinterpret_cast<uint4*>(o);
    }
}

// ------------------------------------------------------------------
// MFMA flash attention v8: composes the session's three proven pieces:
//  - r4's both-swapped 32x32x16 structure: QK^T = mfma(K,Q), PV =
//    mfma(V^T,P); q fully lane-local; P built IN REGISTERS via
//    cvt_pk + one cross-half shfl (no Ps LDS, no lgkm round-trip).
//  - r6's causal pair-tiling: 64-row strips p & 15-p, uniform 17 steps.
//  - r8's max-free softmax (RMSNorm bounds |S|): no running max, no
//    rescale; per-lane l partials, completed in the epilogue.
// Block = 2 waves (128 thr), wave w owns q-rows strip*64+w*32..+32.
// K/V double-buffered in LDS (32KB), counted vmcnt(8), XCD-chunked.
// ------------------------------------------------------------------
__global__ __launch_bounds__(128) void attn_pair32(
    const u16* __restrict__ qkv,  // [2048][3072]
    const u16* __restrict__ vT,   // [16*64][1024]  (rows=d, cols=seq)
    u16* __restrict__ ob)         // [2048][2048]
{
    __shared__ u16 Ks[2][64 * 64];   // [key][d], XOR-swizzled 16B chunks
    __shared__ u16 Vs[2][64 * 64];   // [d][key], XOR-swizzled 16B chunks

    const int bid = blockIdx.x;
    const int L   = (bid & 7) * 64 + (bid >> 3);   // XCD-chunked, bijective
    const int g5  = L >> 5;                        // b*8 + kvh
    const int rem = L & 31;
    const int ha  = rem & 3;
    const int p   = rem >> 2;                      // pair index 0..7
    const int b = g5 >> 3, kvh = g5 & 7;
    const int h = kvh * 4 + ha;
    const int spA = p, spB = 15 - p;               // 64-row strips
    const int tilesA = p + 1;

    const int tid = threadIdx.x, w = tid >> 6, lane = tid & 63;
    const int l31 = lane & 31, hi = lane >> 5;
    const int srow = lane >> 3;
    const int scolsw = (lane & 7) ^ srow;

    const int qA_seq = spA * 64 + w * 32 + l31;
    const int qB_seq = spB * 64 + w * 32 + l31;

    // Q fragments (B-operand of 32x32x16): Q[q=l31][s*16+hi*8 ..+8]
    bf16x8 qfA[4], qfB[4];
    {
        const u16* qra = qkv + (size_t)(b * 1024 + qA_seq) * 3072 + h * 64;
        const u16* qrb = qkv + (size_t)(b * 1024 + qB_seq) * 3072 + h * 64;
        #pragma unroll
        for (int s = 0; s < 4; ++s) {
            qfA[s] = *reinterpret_cast<const bf16x8*>(&qra[s * 16 + hi * 8]);
            qfB[s] = *reinterpret_cast<const bf16x8*>(&qrb[s * 16 + hi * 8]);
        }
    }
    asm volatile("s_waitcnt vmcnt(0)" ::: "memory");   // clean vmcnt for pipeline

    float lrA = 0.f, lrB = 0.f;          // per-lane partial row sums
    f32x16 oaccA[2] = {}, oaccB[2] = {}; // O[d][q=l31], dg -> d 0..31/32..63

    const u16* kbase = qkv + 2048 + kvh * 64;
    const u16* vbase = vT + (size_t)(g5 * 64) * 1024;

// 2 waves stage 64x64 K + 64x64 V: 8 chunks of 8 rows each; wave w does 4.
#define ASTAGE(kt, bb) do {                                                    \
    _Pragma("unroll")                                                          \
    for (int i_ = 0; i_ < 4; ++i_) {                                           \
        int chunk_ = w * 4 + i_;                                               \
        int row_ = chunk_ * 8 + srow;                                          \
        gld_lds16(&kbase[(size_t)(b * 1024 + (kt) * 64 + row_) * 3072          \
                         + scolsw * 8], &Ks[bb][chunk_ * 512]);                \
        gld_lds16(&vbase[(size_t)row_ * 1024 + (kt) * 64 + scolsw * 8],        \
                  &Vs[bb][chunk_ * 512]);                                      \
    } } while (0)

    // one tile-step: both-swapped 32x32, max-free, P in registers
    auto step = [&](int kt, int cur, const bf16x8 (&qf)[4],
                    float& lr, f32x16 (&oacc)[2], int q_seq, bool dz) {
        // QK^T (swapped): D[key][q]
        f32x16 sacc[2] = {};
        #pragma unroll
        for (int gg = 0; gg < 2; ++gg)
            #pragma unroll
            for (int s = 0; s < 4; ++s) {
                const int phys = ((s * 2 + hi) ^ (l31 & 7)) * 8;
                bf16x8 kf = *reinterpret_cast<const bf16x8*>(
                    &Ks[cur][(gg * 32 + l31) * 64 + phys]);
                sacc[gg] = __builtin_amdgcn_mfma_f32_32x32x16_bf16(
                    kf, qf[s], sacc[gg], 0, 0, 0);
            }

        // max-free softmax (base-2); masked -> exp2(-huge) = 0
        const float SC = 0.18033688f;      // 0.125 * log2(e)
        float pv[2][16];
        #pragma unroll
        for (int gg = 0; gg < 2; ++gg)
            #pragma unroll
            for (int r = 0; r < 16; ++r) {
                float v = sacc[gg][r] * SC;
                if (dz) {
                    const int key = kt * 64 + gg * 32
                                  + (r & 3) + 8 * (r >> 2) + 4 * hi;
                    if (key > q_seq) v = -1e30f;
                }
                float e = exp2f(v);
                pv[gg][r] = e;
                lr += e;                   // per-lane partial (half the keys;
            }                              //  completed via shfl in epilogue)

        // build P fragments (B-operand) in registers — r4-verified
        bf16x8 pfrag[4];
        #pragma unroll
        for (int gg = 0; gg < 2; ++gg)
            #pragma unroll
            for (int hh = 0; hh < 2; ++hh) {
                const int r0 = hh * 8;
                u32 Aw = cvtpk(pv[gg][r0+0], pv[gg][r0+1]);
                u32 Bw = cvtpk(pv[gg][r0+2], pv[gg][r0+3]);
                u32 Cw = cvtpk(pv[gg][r0+4], pv[gg][r0+5]);
                u32 Dw = cvtpk(pv[gg][r0+6], pv[gg][r0+7]);
                u32 Ax = __shfl_xor(Aw, 32), Bx = __shfl_xor(Bw, 32);
                u32 Cx = __shfl_xor(Cw, 32), Dx = __shfl_xor(Dw, 32);
                u32 ww[4];
                ww[0] = hi ? Cx : Aw;
                ww[1] = hi ? Dx : Bw;
                ww[2] = hi ? Cw : Ax;
                ww[3] = hi ? Dw : Bx;
                pfrag[gg * 2 + hh] = *reinterpret_cast<const bf16x8*>(ww);
            }

        // PV (swapped): O[d][q] += V^T[d][key] * P[key][q]
        #pragma unroll
        for (int dg = 0; dg < 2; ++dg)
            #pragma unroll
            for (int s = 0; s < 4; ++s) {
                const int phys = ((s * 2 + hi) ^ (l31 & 7)) * 8;
                bf16x8 vf = *reinterpret_cast<const bf16x8*>(
                    &Vs[cur][(dg * 32 + l31) * 64 + phys]);
                oacc[dg] = __builtin_amdgcn_mfma_f32_32x32x16_bf16(
                    vf, pfrag[s], oacc[dg], 0, 0, 0);
            }
    };

    // unified 17-step schedule: s < tilesA -> strip A (kt=s), else B
    ASTAGE(0, 0);
    for (int s = 0; s <= 16; ++s) {
        const int cur = s & 1;
        if (s < 16) {
            const int sn = s + 1;
            const int ktn = (sn < tilesA) ? sn : (sn - tilesA);
            ASTAGE(ktn, cur ^ 1);
            asm volatile("s_waitcnt vmcnt(8)" ::: "memory");
        } else {
            asm volatile("s_waitcnt vmcnt(0)" ::: "memory");
        }
        __builtin_amdgcn_sched_barrier(0);
        __builtin_amdgcn_s_barrier();
        __builtin_amdgcn_sched_barrier(0);

        if (s < tilesA)
            step(s,          cur, qfA, lrA, oaccA, qA_seq, s == tilesA - 1);
        else
            step(s - tilesA, cur, qfB, lrB, oaccB, qB_seq, s == 16);

        __builtin_amdgcn_sched_barrier(0);
        __builtin_amdgcn_s_barrier();    // all reads of cur done before reuse
    }
#undef ASTAGE

    // epilogues: complete l across the two lane-halves, then normalize.
    // lane owns q=q_seq; d = dg*32 + 8*rq + 4*hi + j
    #pragma unroll
    for (int tt = 0; tt < 2; ++tt) {
        const int q_seq = tt ? qB_seq : qA_seq;
        float lr = tt ? lrB : lrA;
        const float lsum = lr + __shfl_xor(lr, 32);
        const float linv = 1.f / lsum;
        f32x16* oacc = tt ? oaccB : oaccA;
        u16* orow = ob + (size_t)(b * 1024 + q_seq) * 2048 + h * 64;
        #pragma unroll
        for (int dg = 0; dg < 2; ++dg)
            #pragma unroll
            for (int rq = 0; rq < 4; ++rq) {
                u16 o4[4];
                #pragma unroll
                for (int j = 0; j < 4; ++j)
                    o4[j] = f2bf(oacc[dg][rq * 4 + j] * linv);
                *reinterpret_cast<uint2*>(&orow[dg * 32 + 8 * rq + 4 * hi])
                    = *reinterpret_cast<const uint2*>(o4);
            }
    }
}

// ------------------------------------------------------------------
extern "C" void kernel_launch(void* const* d_in, const int* in_sizes, int n_in,
                              void* d_out, int out_size, void* d_ws, size_t ws_size,
                              hipStream_t stream)
{
    const float* hidden = (const float*)d_in[0];
    const float* cosb   = (const float*)d_in[1];
    const float* sinb   = (const float*)d_in[2];
    // d_in[3] = attention_mask (pure causal; handled analytically)
    const float* wq     = (const float*)d_in[4];
    const float* wk     = (const float*)d_in[5];
    const float* wv     = (const float*)d_in[6];
    const float* wo     = (const float*)d_in[7];
    const float* qnw    = (const float*)d_in[8];
    const float* knw    = (const float*)d_in[9];
    float* out = (float*)d_out;

    char* ws = (char*)d_ws;
    u16* hidden_bf = (u16*)ws;                          // [0,8M)
    u16* wqkvT     = (u16*)(ws + ((size_t)8  << 20));   // [8,20M) -> later attn_bf
    u16* attn_bf   = (u16*)(ws + ((size_t)8  << 20));
    u16* qkv_bf    = (u16*)(ws + ((size_t)20 << 20));   // [20,32M)
    u16* v_bfT     = (u16*)(ws + ((size_t)32 << 20));   // [32,34M)
    u16* woT       = (u16*)(ws + ((size_t)34 << 20));   // [34,42M)

    // hidden -> bf16, wq|wk|wv pack-transpose, wo transpose
    preproc1<<<4608, 256, 0, stream>>>(hidden, wq, wk, wv, wo,
                                       hidden_bf, wqkvT, woT);

    // fused QKV projection: [2048,2048] @ [2048,3072] -> bf16 [2048,3072]
    gemm_bt<true><<<768, 256, 0, stream>>>(hidden_bf, wqkvT, qkv_bf,
                                           2048, 3072, 2048);

    // RMSNorm + RoPE for Q and K (in place) + V transpose
    rmsnorm_rope_vt<<<2304, 256, 0, stream>>>(qkv_bf, qnw, knw, cosb, sinb, v_bfT);

    // attention -> attn_bf (aliases wqkvT region, free after QKV GEMM)
    attn_pair32<<<512, 128, 0, stream>>>(qkv_bf, v_bfT, attn_bf);

    // output projection: [2048,2048] @ woT^T -> fp32 out
    gemm_bt<false><<<512, 256, 0, stream>>>(attn_bf, woT, out,
                                            2048, 2048, 2048);
}

// Round 11
// 130.396 us; speedup vs baseline: 1.1094x; 1.1067x over previous
//
#include <hip/hip_runtime.h>

#define B_    2
#define S_    1024
#define NH_   32
#define NKV_  8
#define T_    (B_*S_)

typedef unsigned short u16;
typedef unsigned int u32;
typedef __attribute__((ext_vector_type(8))) short bf16x8;
typedef __attribute__((ext_vector_type(4))) float f32x4;

__device__ __forceinline__ float bf2f(u16 u) {
    union { float f; unsigned int i; } c; c.i = ((unsigned int)u) << 16; return c.f;
}
__device__ __forceinline__ u16 f2bf(float f) {
    union { float f; unsigned int u; } c; c.f = f;
    return (u16)((c.u + 0x7FFFu + ((c.u >> 16) & 1u)) >> 16);
}

// async global->LDS, 16B per lane; LDS dest = wave-uniform base + lane*16 (linear)
__device__ __forceinline__ void gld_lds16(const void* g, void* s) {
    __builtin_amdgcn_global_load_lds(
        (const __attribute__((address_space(1))) void*)g,
        (__attribute__((address_space(3))) void*)s,
        16, 0, 0);
}

// ------------------------------------------------------------------
// preproc1: [0,2048) hidden f32->bf16; [2048,3584) wqkv pack-transpose;
//           [3584,4608) wo transpose -> woT bf16 [2048][2048]
// ------------------------------------------------------------------
__global__ __launch_bounds__(256) void preproc1(
    const float* __restrict__ hidden, const float* __restrict__ wq,
    const float* __restrict__ wk, const float* __restrict__ wv,
    const float* __restrict__ wo,
    u16* __restrict__ hidden_bf, u16* __restrict__ wqkvT, u16* __restrict__ woT)
{
    __shared__ float t[64][65];
    const int bid = blockIdx.x, tid = threadIdx.x;
    if (bid < 2048) {
        int i = (bid * 256 + tid) * 8;
        float4 v0 = *reinterpret_cast<const float4*>(&hidden[i]);
        float4 v1 = *reinterpret_cast<const float4*>(&hidden[i + 4]);
        u16 o[8] = { f2bf(v0.x), f2bf(v0.y), f2bf(v0.z), f2bf(v0.w),
                     f2bf(v1.x), f2bf(v1.y), f2bf(v1.z), f2bf(v1.w) };
        *reinterpret_cast<uint4*>(&hidden_bf[i]) = *reinterpret_cast<uint4*>(o);
        return;
    }
    const float* src; int scol, sN, n0, k0;
    u16* dst; int dK;
    if (bid < 3584) {
        const int tt = bid - 2048;
        n0 = (tt % 48) * 64; k0 = (tt / 48) * 64;
        if (n0 < 2048)      { src = wq; scol = n0;        sN = 2048; }
        else if (n0 < 2560) { src = wk; scol = n0 - 2048; sN = 512;  }
        else                { src = wv; scol = n0 - 2560; sN = 512;  }
        dst = wqkvT; dK = 2048;
    } else {
        const int tt = bid - 3584;
        n0 = (tt % 32) * 64; k0 = (tt / 32) * 64;
        src = wo; scol = n0; sN = 2048;
        dst = woT; dK = 2048;
    }
    #pragma unroll
    for (int i = 0; i < 16; ++i) {
        int e = i * 256 + tid, r = e >> 6, c = e & 63;
        t[r][c] = src[(size_t)(k0 + r) * sN + scol + c];
    }
    __syncthreads();
    #pragma unroll
    for (int i = 0; i < 16; ++i) {
        int e = i * 256 + tid, rr = e >> 6, cc = e & 63;
        dst[(size_t)(n0 + rr) * dK + k0 + cc] = f2bf(t[cc][rr]);
    }
}

// ------------------------------------------------------------------
// bf16 MFMA GEMM, B^T input. C[M,N] = A[M,K] @ Bt[N,K]^T
// 128x64 tile, BK=64, 4 waves (2x2), wave-tile 64x32, T2 XOR-swizzled
// LDS, double-buffered counted-vmcnt staging, T1 XCD-chunked 1D grid.
// ------------------------------------------------------------------
template<bool OUT_BF16>
__global__ __launch_bounds__(256) void gemm_bt(
    const u16* __restrict__ A, const u16* __restrict__ Bt,
    void* __restrict__ Cv, int M, int N, int K)
{
    __shared__ u16 As[2][128 * 64];
    __shared__ u16 Bs[2][64 * 64];
    const int MB = M >> 7;
    const int cpx = gridDim.x >> 3;
    const int L = (blockIdx.x & 7) * cpx + (blockIdx.x >> 3);  // XCD-chunked
    const int bm = (L % MB) * 128, bn = (L / MB) * 64;
    const int tid = threadIdx.x;
    const int w = tid >> 6, lane = tid & 63;
    const int wr = w >> 1, wc = w & 1;
    const int l15 = lane & 15, lg = lane >> 4;
    const int srow = lane >> 3;                       // 0..7
    const int scolsw = (lane & 7) ^ srow;             // swizzled source 16B-chunk

    f32x4 acc[4][2] = {};
    const int nk = K >> 6;

#define GSTAGE(ks, bb) do {                                                    \
    const int kofs = (ks) * 64;                                                \
    _Pragma("unroll")                                                          \
    for (int i_ = 0; i_ < 4; ++i_) {                                           \
        int chunk_ = w * 4 + i_;                                               \
        int row_ = chunk_ * 8 + srow;                                          \
        gld_lds16(&A[(size_t)(bm + row_) * K + kofs + scolsw * 8],             \
                  &As[bb][chunk_ * 512]);                                      \
    }                                                                          \
    _Pragma("unroll")                                                          \
    for (int j_ = 0; j_ < 2; ++j_) {                                           \
        int chunk_ = w * 2 + j_;                                               \
        int row_ = chunk_ * 8 + srow;                                          \
        gld_lds16(&Bt[(size_t)(bn + row_) * K + kofs + scolsw * 8],            \
                  &Bs[bb][chunk_ * 512]);                                      \
    } } while (0)

    GSTAGE(0, 0);
    for (int ks = 0; ks < nk; ++ks) {
        const int cur = ks & 1;
        if (ks + 1 < nk) {
            GSTAGE(ks + 1, cur ^ 1);
            asm volatile("s_waitcnt vmcnt(6)" ::: "memory");
        } else {
            asm volatile("s_waitcnt vmcnt(0)" ::: "memory");
        }
        __builtin_amdgcn_sched_barrier(0);
        __builtin_amdgcn_s_barrier();
        __builtin_amdgcn_sched_barrier(0);

        #pragma unroll
        for (int kk = 0; kk < 2; ++kk) {
            const int phys = ((kk * 4 + lg) ^ (l15 & 7)) * 8;
            bf16x8 a[4], b[2];
            #pragma unroll
            for (int m = 0; m < 4; ++m)
                a[m] = *reinterpret_cast<const bf16x8*>(
                    &As[cur][(wr * 64 + m * 16 + l15) * 64 + phys]);
            #pragma unroll
            for (int n = 0; n < 2; ++n)
                b[n] = *reinterpret_cast<const bf16x8*>(
                    &Bs[cur][(wc * 32 + n * 16 + l15) * 64 + phys]);
            #pragma unroll
            for (int m = 0; m < 4; ++m)
                #pragma unroll
                for (int n = 0; n < 2; ++n)
                    acc[m][n] = __builtin_amdgcn_mfma_f32_16x16x32_bf16(
                        a[m], b[n], acc[m][n], 0, 0, 0);
        }
        __builtin_amdgcn_sched_barrier(0);
        __builtin_amdgcn_s_barrier();   // protect buffer reuse next iter
    }
#undef GSTAGE

    const int orow0 = bm + wr * 64, ocol0 = bn + wc * 32;
    #pragma unroll
    for (int m = 0; m < 4; ++m)
        #pragma unroll
        for (int n = 0; n < 2; ++n)
            #pragma unroll
            for (int r = 0; r < 4; ++r) {
                int row = orow0 + m * 16 + lg * 4 + r;
                int col = ocol0 + n * 16 + l15;
                float v = acc[m][n][r];
                if (OUT_BF16)
                    ((u16*)Cv)[(size_t)row * N + col] = f2bf(v);
                else
                    ((float*)Cv)[(size_t)row * N + col] = v;
            }
}

// ------------------------------------------------------------------
// Merged RMSNorm+RoPE (blocks [0,2048), token per block) and
// V transpose (blocks [2048,2304)) -> vT [(b*8+kvh)*64+d][1024]
// ------------------------------------------------------------------
template<int DIM>
__device__ __forceinline__ void rms_rope_row(
    u16* base, const float* __restrict__ w,
    const float* __restrict__ cs, const float* __restrict__ sn,
    float* row, float* red, int tid)
{
    float ss = 0.f;
    for (int i0 = tid * 8; i0 < DIM; i0 += 2048) {
        uint4 u = *reinterpret_cast<const uint4*>(&base[i0]);
        const u16* us = reinterpret_cast<const u16*>(&u);
        #pragma unroll
        for (int j = 0; j < 8; ++j) { float f = bf2f(us[j]); row[i0 + j] = f; ss += f * f; }
    }
    #pragma unroll
    for (int off = 1; off < 64; off <<= 1) ss += __shfl_xor(ss, off);
    if ((tid & 63) == 0) red[tid >> 6] = ss;
    __syncthreads();
    const float rstd = rsqrtf((red[0] + red[1] + red[2] + red[3]) * (1.0f / DIM) + 1e-6f);

    for (int i0 = tid * 8; i0 < DIM; i0 += 2048) {
        u16 o[8];
        #pragma unroll
        for (int j = 0; j < 8; ++j) {
            int i = i0 + j, dh = i & 63, bb = i & ~63;
            int oi = (dh < 32) ? bb + dh + 32 : bb + dh - 32;
            float y     = row[i]  * rstd * w[i];
            float other = row[oi] * rstd * w[oi];
            if (dh < 32) other = -other;
            o[j] = f2bf(y * cs[dh] + other * sn[dh]);
        }
        *reinterpret_cast<uint4*>(&base[i0]) = *reinterpret_cast<uint4*>(o);
    }
}

__global__ __launch_bounds__(256) void rmsnorm_rope_vt(
    u16* __restrict__ x, const float* __restrict__ qnw, const float* __restrict__ knw,
    const float* __restrict__ cosb, const float* __restrict__ sinb,
    u16* __restrict__ vT)
{
    __shared__ float smem[2304];          // 9216 B, aliased
    const int bid = blockIdx.x, tid = threadIdx.x;
    if (bid < 2048) {
        const int t = bid;
        float* row = smem;
        float* red = smem + 2048;
        const float* cs = cosb + (size_t)t * 64;
        const float* sn = sinb + (size_t)t * 64;
        rms_rope_row<2048>(x + (size_t)t * 3072,        qnw, cs, sn, row, red, tid);
        __syncthreads();
        rms_rope_row<512 >(x + (size_t)t * 3072 + 2048, knw, cs, sn, row, red, tid);
        return;
    }
    // V transpose
    u16 (*tu)[72] = reinterpret_cast<u16(*)[72]>(smem);
    const int bid2 = bid - 2048;
    const int hd = bid2 % 16;              // b*8 + kvh
    const int s0 = (bid2 / 16) * 64;
    const int b = hd >> 3, kvh = hd & 7;
    #pragma unroll
    for (int i = 0; i < 2; ++i) {
        int chunk = i * 256 + tid;
        int r = chunk >> 3, c8 = (chunk & 7) * 8;
        uint4 u = *reinterpret_cast<const uint4*>(
            &x[(size_t)(b * 1024 + s0 + r) * 3072 + 2560 + kvh * 64 + c8]);
        *reinterpret_cast<uint4*>(&tu[r][c8]) = u;
    }
    __syncthreads();
    #pragma unroll
    for (int i = 0; i < 2; ++i) {
        int chunk = i * 256 + tid;
        int d = chunk >> 3, c8 = (chunk & 7) * 8;
        u16 o[8];
        #pragma unroll
        for (int j = 0; j < 8; ++j) o[j] = tu[c8 + j][d];
        *reinterpret_cast<uint4*>(&vT[((size_t)(hd * 64 + d)) * 1024 + s0 + c8])
            = *reinterpret_cast<uint4*>(o);
    }
}

// ------------------------------------------------------------------
// MFMA flash attention v9 = r8's proven kernel + 1-deep cross-step
// software pipeline: at step s, PV(s-1) runs BEFORE QK(s)/softmax(s).
// PV(s-1) is independent of QK(s) -> two MFMA chains interleave and
// softmax VALU overlaps PV; the Ps write->read round-trip spans a
// full step (its lgkm wait is a retired no-op; same-wave DS program
// order covers the RAW). Buffer lifetimes: V triple-buffered,
// Ps double-buffered, K stays 2-deep. LDS 56KB -> 2 blocks/CU
// (8 waves/CU, same as r8). Max-free softmax, pair-tiled 17+1 steps.
// ------------------------------------------------------------------
__global__ __launch_bounds__(256) void attn_pipe(
    const u16* __restrict__ qkv,  // [2048][3072]
    const u16* __restrict__ vT,   // [16*64][1024]
    u16* __restrict__ ob)         // [2048][2048]
{
    __shared__ u16 Ks[2][64 * 64];
    __shared__ u16 Vs[3][64 * 64];
    __shared__ u16 Ps[4][2][16 * 64];

    const int bid = blockIdx.x;
    const int L   = (bid & 7) * 64 + (bid >> 3);   // XCD-chunked, bijective
    const int g5  = L >> 5;                        // b*8 + kvh
    const int rem = L & 31;
    const int ha  = rem & 3;
    const int p   = rem >> 2;                      // pair index 0..7
    const int b = g5 >> 3, kvh = g5 & 7;
    const int h = kvh * 4 + ha;
    const int qtA = p, qtB = 15 - p;
    const int tilesA = p + 1;                      // steps 0..p = strip A

    const int tid = threadIdx.x, w = tid >> 6, lane = tid & 63;
    const int l15 = lane & 15, lg = lane >> 4;
    const int srow = lane >> 3;
    const int scolsw = (lane & 7) ^ srow;

    // Q fragments for both tiles (q-row = l15 of wave's 16)
    bf16x8 qfA[2], qfB[2];
    {
        const size_t rA = (size_t)(b * 1024 + qtA * 64 + w * 16 + l15);
        const size_t rB = (size_t)(b * 1024 + qtB * 64 + w * 16 + l15);
        #pragma unroll
        for (int kk = 0; kk < 2; ++kk) {
            qfA[kk] = *reinterpret_cast<const bf16x8*>(
                &qkv[rA * 3072 + h * 64 + kk * 32 + lg * 8]);
            qfB[kk] = *reinterpret_cast<const bf16x8*>(
                &qkv[rB * 3072 + h * 64 + kk * 32 + lg * 8]);
        }
    }
    asm volatile("s_waitcnt vmcnt(0)" ::: "memory");  // clean vmcnt for pipeline

    float lrA = 0.f, lrB = 0.f;          // per-lane partial row sums
    f32x4 oaccA[4] = {}, oaccB[4] = {};

    const u16* kbase = qkv + 2048 + kvh * 64;
    const u16* vbase = vT + (size_t)(g5 * 64) * 1024;
    const int qgA = qtA * 64 + w * 16 + l15;
    const int qgB = qtB * 64 + w * 16 + l15;

#define ASTAGE(kt, kb, vb) do {                                                \
    _Pragma("unroll")                                                          \
    for (int i_ = 0; i_ < 2; ++i_) {                                           \
        int chunk_ = w * 2 + i_;                                               \
        int row_ = chunk_ * 8 + srow;                                          \
        gld_lds16(&kbase[(size_t)(b * 1024 + (kt) * 64 + row_) * 3072          \
                         + scolsw * 8], &Ks[kb][chunk_ * 512]);                \
        gld_lds16(&vbase[(size_t)row_ * 1024 + (kt) * 64 + scolsw * 8],        \
                  &Vs[vb][chunk_ * 512]);                                      \
    } } while (0)

    // QK^T + max-free softmax + pack into Ps[w][par]
    auto qksm = [&](int kt, int kcur, int par, const bf16x8 (&qf)[2],
                    float& lr, int qg, bool dz) {
        f32x4 sacc[4] = {};
        #pragma unroll
        for (int kk = 0; kk < 2; ++kk) {
            const int phys = ((kk * 4 + lg) ^ (l15 & 7)) * 8;
            #pragma unroll
            for (int m = 0; m < 4; ++m) {
                bf16x8 kf = *reinterpret_cast<const bf16x8*>(
                    &Ks[kcur][(m * 16 + l15) * 64 + phys]);
                sacc[m] = __builtin_amdgcn_mfma_f32_16x16x32_bf16(
                    kf, qf[kk], sacc[m], 0, 0, 0);
            }
        }
        float ls = 0.f;
        #pragma unroll
        for (int m = 0; m < 4; ++m) {
            u16 pk[4];
            #pragma unroll
            for (int r = 0; r < 4; ++r) {
                float v = sacc[m][r] * 0.18033688f;   // 0.125 * log2(e)
                if (dz && (kt * 64 + m * 16 + lg * 4 + r > qg)) v = -1e30f;
                float e = exp2f(v);
                ls += e;
                pk[r] = f2bf(e);
            }
            const int keyc = m * 16 + lg * 4;
            const int phys = (keyc >> 3) ^ (l15 & 7);
            *reinterpret_cast<uint2*>(
                &Ps[w][par][l15 * 64 + phys * 8 + (keyc & 7)])
                = *reinterpret_cast<const uint2*>(pk);
        }
        lr += ls;                         // per-lane partial; reduce at end
    };

    // PV using Ps[w][par] and Vs[vidx]
    auto pv = [&](int par, int vidx, f32x4 (&oacc)[4]) {
        #pragma unroll
        for (int kk = 0; kk < 2; ++kk) {
            const int phys = ((kk * 4 + lg) ^ (l15 & 7)) * 8;
            bf16x8 pf = *reinterpret_cast<const bf16x8*>(
                &Ps[w][par][l15 * 64 + phys]);
            #pragma unroll
            for (int d = 0; d < 4; ++d) {
                bf16x8 vf = *reinterpret_cast<const bf16x8*>(
                    &Vs[vidx][(d * 16 + l15) * 64 + phys]);
                oacc[d] = __builtin_amdgcn_mfma_f32_16x16x32_bf16(
                    pf, vf, oacc[d], 0, 0, 0);
            }
        }
    };

    // pipelined schedule: 17 tile-works + 1 drain step.
    // job(s): s<tilesA -> strip A (kt=s) ; else strip B (kt=s-tilesA)
    ASTAGE(0, 0, 0);
    for (int s = 0; s <= 17; ++s) {
        if (s <= 16) {
            if (s < 16) {
                const int sn = s + 1;
                const int ktn = (sn < tilesA) ? sn : (sn - tilesA);
                ASTAGE(ktn, sn & 1, sn % 3);
                asm volatile("s_waitcnt vmcnt(4)" ::: "memory");
            } else {
                asm volatile("s_waitcnt vmcnt(0)" ::: "memory");
            }
            __builtin_amdgcn_sched_barrier(0);
            __builtin_amdgcn_s_barrier();
            __builtin_amdgcn_sched_barrier(0);
        }

        // PV of previous tile-work (independent of this step's QK)
        if (s >= 1) {
            const int t = s - 1;
            if (t < tilesA) pv(t & 1, t % 3, oaccA);
            else            pv(t & 1, t % 3, oaccB);
        }
        // QK + softmax + pack of current tile-work
        if (s <= 16) {
            if (s < tilesA)
                qksm(s, s & 1, s & 1, qfA, lrA, qgA, s == tilesA - 1);
            else
                qksm(s - tilesA, s & 1, s & 1, qfB, lrB, qgB, s == 16);
        }

        __builtin_amdgcn_sched_barrier(0);
        __builtin_amdgcn_s_barrier();    // all reads done before buffer reuse
    }
#undef ASTAGE

    // epilogues: reduce l across the 4 lane-groups once, then normalize.
    #pragma unroll
    for (int tt = 0; tt < 2; ++tt) {
        const int qt = tt ? qtB : qtA;
        float lsum = tt ? lrB : lrA;
        lsum += __shfl_xor(lsum, 16);
        lsum += __shfl_xor(lsum, 32);
        f32x4* oacc = tt ? oaccB : oaccA;
        float linv[4];
        #pragma unroll
        for (int r = 0; r < 4; ++r) {
            float lv = __shfl(lsum, (lane & 48) + ((lane >> 4) & 3) * 4 + r);
            linv[r] = 1.f / lv;
        }
        #pragma unroll
        for (int d = 0; d < 4; ++d)
            #pragma unroll
            for (int r = 0; r < 4; ++r)
                ob[(size_t)(b * 1024 + qt * 64 + w * 16 + lg * 4 + r) * 2048
                   + h * 64 + d * 16 + l15] = f2bf(oacc[d][r] * linv[r]);
    }
}

// ------------------------------------------------------------------
extern "C" void kernel_launch(void* const* d_in, const int* in_sizes, int n_in,
                              void* d_out, int out_size, void* d_ws, size_t ws_size,
                              hipStream_t stream)
{
    const float* hidden = (const float*)d_in[0];
    const float* cosb   = (const float*)d_in[1];
    const float* sinb   = (const float*)d_in[2];
    // d_in[3] = attention_mask (pure causal; handled analytically)
    const float* wq     = (const float*)d_in[4];
    const float* wk     = (const float*)d_in[5];
    const float* wv     = (const float*)d_in[6];
    const float* wo     = (const float*)d_in[7];
    const float* qnw    = (const float*)d_in[8];
    const float* knw    = (const float*)d_in[9];
    float* out = (float*)d_out;

    char* ws = (char*)d_ws;
    u16* hidden_bf = (u16*)ws;                          // [0,8M)
    u16* wqkvT     = (u16*)(ws + ((size_t)8  << 20));   // [8,20M) -> later attn_bf
    u16* attn_bf   = (u16*)(ws + ((size_t)8  << 20));
    u16* qkv_bf    = (u16*)(ws + ((size_t)20 << 20));   // [20,32M)
    u16* v_bfT     = (u16*)(ws + ((size_t)32 << 20));   // [32,34M)
    u16* woT       = (u16*)(ws + ((size_t)34 << 20));   // [34,42M)

    // hidden -> bf16, wq|wk|wv pack-transpose, wo transpose
    preproc1<<<4608, 256, 0, stream>>>(hidden, wq, wk, wv, wo,
                                       hidden_bf, wqkvT, woT);

    // fused QKV projection: [2048,2048] @ [2048,3072] -> bf16 [2048,3072]
    gemm_bt<true><<<768, 256, 0, stream>>>(hidden_bf, wqkvT, qkv_bf,
                                           2048, 3072, 2048);

    // RMSNorm + RoPE for Q and K (in place) + V transpose
    rmsnorm_rope_vt<<<2304, 256, 0, stream>>>(qkv_bf, qnw, knw, cosb, sinb, v_bfT);

    // attention -> attn_bf (aliases wqkvT region, free after QKV GEMM)
    attn_pipe<<<512, 256, 0, stream>>>(qkv_bf, v_bfT, attn_bf);

    // output projection: [2048,2048] @ woT^T -> fp32 out
    gemm_bt<false><<<512, 256, 0, stream>>>(attn_bf, woT, out,
                                            2048, 2048, 2048);
}

// Round 12
// 126.703 us; speedup vs baseline: 1.1418x; 1.0291x over previous
//
#include <hip/hip_runtime.h>

#define B_    2
#define S_    1024
#define NH_   32
#define NKV_  8
#define T_    (B_*S_)

typedef unsigned short u16;
typedef unsigned int u32;
typedef __attribute__((ext_vector_type(8))) short bf16x8;
typedef __attribute__((ext_vector_type(4))) float f32x4;

__device__ __forceinline__ float bf2f(u16 u) {
    union { float f; unsigned int i; } c; c.i = ((unsigned int)u) << 16; return c.f;
}
__device__ __forceinline__ u16 f2bf(float f) {
    union { float f; unsigned int u; } c; c.f = f;
    return (u16)((c.u + 0x7FFFu + ((c.u >> 16) & 1u)) >> 16);
}

// async global->LDS, 16B per lane; LDS dest = wave-uniform base + lane*16 (linear)
__device__ __forceinline__ void gld_lds16(const void* g, void* s) {
    __builtin_amdgcn_global_load_lds(
        (const __attribute__((address_space(1))) void*)g,
        (__attribute__((address_space(3))) void*)s,
        16, 0, 0);
}

// ------------------------------------------------------------------
// preproc1: [0,2048) hidden f32->bf16; [2048,3584) wqkv pack-transpose;
//           [3584,4608) wo transpose -> woT bf16 [2048][2048]
// ------------------------------------------------------------------
__global__ __launch_bounds__(256) void preproc1(
    const float* __restrict__ hidden, const float* __restrict__ wq,
    const float* __restrict__ wk, const float* __restrict__ wv,
    const float* __restrict__ wo,
    u16* __restrict__ hidden_bf, u16* __restrict__ wqkvT, u16* __restrict__ woT)
{
    __shared__ float t[64][65];
    const int bid = blockIdx.x, tid = threadIdx.x;
    if (bid < 2048) {
        int i = (bid * 256 + tid) * 8;
        float4 v0 = *reinterpret_cast<const float4*>(&hidden[i]);
        float4 v1 = *reinterpret_cast<const float4*>(&hidden[i + 4]);
        u16 o[8] = { f2bf(v0.x), f2bf(v0.y), f2bf(v0.z), f2bf(v0.w),
                     f2bf(v1.x), f2bf(v1.y), f2bf(v1.z), f2bf(v1.w) };
        *reinterpret_cast<uint4*>(&hidden_bf[i]) = *reinterpret_cast<uint4*>(o);
        return;
    }
    const float* src; int scol, sN, n0, k0;
    u16* dst; int dK;
    if (bid < 3584) {
        const int tt = bid - 2048;
        n0 = (tt % 48) * 64; k0 = (tt / 48) * 64;
        if (n0 < 2048)      { src = wq; scol = n0;        sN = 2048; }
        else if (n0 < 2560) { src = wk; scol = n0 - 2048; sN = 512;  }
        else                { src = wv; scol = n0 - 2560; sN = 512;  }
        dst = wqkvT; dK = 2048;
    } else {
        const int tt = bid - 3584;
        n0 = (tt % 32) * 64; k0 = (tt / 32) * 64;
        src = wo; scol = n0; sN = 2048;
        dst = woT; dK = 2048;
    }
    #pragma unroll
    for (int i = 0; i < 16; ++i) {
        int e = i * 256 + tid, r = e >> 6, c = e & 63;
        t[r][c] = src[(size_t)(k0 + r) * sN + scol + c];
    }
    __syncthreads();
    #pragma unroll
    for (int i = 0; i < 16; ++i) {
        int e = i * 256 + tid, rr = e >> 6, cc = e & 63;
        dst[(size_t)(n0 + rr) * dK + k0 + cc] = f2bf(t[cc][rr]);
    }
}

// ------------------------------------------------------------------
// bf16 MFMA GEMM, B^T input. C[M,N] = A[M,K] @ Bt[N,K]^T
// 128x64 tile, BK=64, 4 waves (2x2), wave-tile 64x32, T2 XOR-swizzled
// LDS, double-buffered counted-vmcnt staging, T1 XCD-chunked 1D grid.
// ------------------------------------------------------------------
template<bool OUT_BF16>
__global__ __launch_bounds__(256) void gemm_bt(
    const u16* __restrict__ A, const u16* __restrict__ Bt,
    void* __restrict__ Cv, int M, int N, int K)
{
    __shared__ u16 As[2][128 * 64];
    __shared__ u16 Bs[2][64 * 64];
    const int MB = M >> 7;
    const int cpx = gridDim.x >> 3;
    const int L = (blockIdx.x & 7) * cpx + (blockIdx.x >> 3);  // XCD-chunked
    const int bm = (L % MB) * 128, bn = (L / MB) * 64;
    const int tid = threadIdx.x;
    const int w = tid >> 6, lane = tid & 63;
    const int wr = w >> 1, wc = w & 1;
    const int l15 = lane & 15, lg = lane >> 4;
    const int srow = lane >> 3;                       // 0..7
    const int scolsw = (lane & 7) ^ srow;             // swizzled source 16B-chunk

    f32x4 acc[4][2] = {};
    const int nk = K >> 6;

#define GSTAGE(ks, bb) do {                                                    \
    const int kofs = (ks) * 64;                                                \
    _Pragma("unroll")                                                          \
    for (int i_ = 0; i_ < 4; ++i_) {                                           \
        int chunk_ = w * 4 + i_;                                               \
        int row_ = chunk_ * 8 + srow;                                          \
        gld_lds16(&A[(size_t)(bm + row_) * K + kofs + scolsw * 8],             \
                  &As[bb][chunk_ * 512]);                                      \
    }                                                                          \
    _Pragma("unroll")                                                          \
    for (int j_ = 0; j_ < 2; ++j_) {                                           \
        int chunk_ = w * 2 + j_;                                               \
        int row_ = chunk_ * 8 + srow;                                          \
        gld_lds16(&Bt[(size_t)(bn + row_) * K + kofs + scolsw * 8],            \
                  &Bs[bb][chunk_ * 512]);                                      \
    } } while (0)

    GSTAGE(0, 0);
    for (int ks = 0; ks < nk; ++ks) {
        const int cur = ks & 1;
        if (ks + 1 < nk) {
            GSTAGE(ks + 1, cur ^ 1);
            asm volatile("s_waitcnt vmcnt(6)" ::: "memory");
        } else {
            asm volatile("s_waitcnt vmcnt(0)" ::: "memory");
        }
        __builtin_amdgcn_sched_barrier(0);
        __builtin_amdgcn_s_barrier();
        __builtin_amdgcn_sched_barrier(0);

        #pragma unroll
        for (int kk = 0; kk < 2; ++kk) {
            const int phys = ((kk * 4 + lg) ^ (l15 & 7)) * 8;
            bf16x8 a[4], b[2];
            #pragma unroll
            for (int m = 0; m < 4; ++m)
                a[m] = *reinterpret_cast<const bf16x8*>(
                    &As[cur][(wr * 64 + m * 16 + l15) * 64 + phys]);
            #pragma unroll
            for (int n = 0; n < 2; ++n)
                b[n] = *reinterpret_cast<const bf16x8*>(
                    &Bs[cur][(wc * 32 + n * 16 + l15) * 64 + phys]);
            #pragma unroll
            for (int m = 0; m < 4; ++m)
                #pragma unroll
                for (int n = 0; n < 2; ++n)
                    acc[m][n] = __builtin_amdgcn_mfma_f32_16x16x32_bf16(
                        a[m], b[n], acc[m][n], 0, 0, 0);
        }
        __builtin_amdgcn_sched_barrier(0);
        __builtin_amdgcn_s_barrier();   // protect buffer reuse next iter
    }
#undef GSTAGE

    const int orow0 = bm + wr * 64, ocol0 = bn + wc * 32;
    #pragma unroll
    for (int m = 0; m < 4; ++m)
        #pragma unroll
        for (int n = 0; n < 2; ++n)
            #pragma unroll
            for (int r = 0; r < 4; ++r) {
                int row = orow0 + m * 16 + lg * 4 + r;
                int col = ocol0 + n * 16 + l15;
                float v = acc[m][n][r];
                if (OUT_BF16)
                    ((u16*)Cv)[(size_t)row * N + col] = f2bf(v);
                else
                    ((float*)Cv)[(size_t)row * N + col] = v;
            }
}

// ------------------------------------------------------------------
// Merged RMSNorm+RoPE (blocks [0,2048), token per block) and
// V transpose (blocks [2048,2304)) -> vT [(b*8+kvh)*64+d][1024]
// ------------------------------------------------------------------
template<int DIM>
__device__ __forceinline__ void rms_rope_row(
    u16* base, const float* __restrict__ w,
    const float* __restrict__ cs, const float* __restrict__ sn,
    float* row, float* red, int tid)
{
    float ss = 0.f;
    for (int i0 = tid * 8; i0 < DIM; i0 += 2048) {
        uint4 u = *reinterpret_cast<const uint4*>(&base[i0]);
        const u16* us = reinterpret_cast<const u16*>(&u);
        #pragma unroll
        for (int j = 0; j < 8; ++j) { float f = bf2f(us[j]); row[i0 + j] = f; ss += f * f; }
    }
    #pragma unroll
    for (int off = 1; off < 64; off <<= 1) ss += __shfl_xor(ss, off);
    if ((tid & 63) == 0) red[tid >> 6] = ss;
    __syncthreads();
    const float rstd = rsqrtf((red[0] + red[1] + red[2] + red[3]) * (1.0f / DIM) + 1e-6f);

    for (int i0 = tid * 8; i0 < DIM; i0 += 2048) {
        u16 o[8];
        #pragma unroll
        for (int j = 0; j < 8; ++j) {
            int i = i0 + j, dh = i & 63, bb = i & ~63;
            int oi = (dh < 32) ? bb + dh + 32 : bb + dh - 32;
            float y     = row[i]  * rstd * w[i];
            float other = row[oi] * rstd * w[oi];
            if (dh < 32) other = -other;
            o[j] = f2bf(y * cs[dh] + other * sn[dh]);
        }
        *reinterpret_cast<uint4*>(&base[i0]) = *reinterpret_cast<uint4*>(o);
    }
}

__global__ __launch_bounds__(256) void rmsnorm_rope_vt(
    u16* __restrict__ x, const float* __restrict__ qnw, const float* __restrict__ knw,
    const float* __restrict__ cosb, const float* __restrict__ sinb,
    u16* __restrict__ vT)
{
    __shared__ float smem[2304];          // 9216 B, aliased
    const int bid = blockIdx.x, tid = threadIdx.x;
    if (bid < 2048) {
        const int t = bid;
        float* row = smem;
        float* red = smem + 2048;
        const float* cs = cosb + (size_t)t * 64;
        const float* sn = sinb + (size_t)t * 64;
        rms_rope_row<2048>(x + (size_t)t * 3072,        qnw, cs, sn, row, red, tid);
        __syncthreads();
        rms_rope_row<512 >(x + (size_t)t * 3072 + 2048, knw, cs, sn, row, red, tid);
        return;
    }
    // V transpose
    u16 (*tu)[72] = reinterpret_cast<u16(*)[72]>(smem);
    const int bid2 = bid - 2048;
    const int hd = bid2 % 16;              // b*8 + kvh
    const int s0 = (bid2 / 16) * 64;
    const int b = hd >> 3, kvh = hd & 7;
    #pragma unroll
    for (int i = 0; i < 2; ++i) {
        int chunk = i * 256 + tid;
        int r = chunk >> 3, c8 = (chunk & 7) * 8;
        uint4 u = *reinterpret_cast<const uint4*>(
            &x[(size_t)(b * 1024 + s0 + r) * 3072 + 2560 + kvh * 64 + c8]);
        *reinterpret_cast<uint4*>(&tu[r][c8]) = u;
    }
    __syncthreads();
    #pragma unroll
    for (int i = 0; i < 2; ++i) {
        int chunk = i * 256 + tid;
        int d = chunk >> 3, c8 = (chunk & 7) * 8;
        u16 o[8];
        #pragma unroll
        for (int j = 0; j < 8; ++j) o[j] = tu[c8 + j][d];
        *reinterpret_cast<uint4*>(&vT[((size_t)(hd * 64 + d)) * 1024 + s0 + c8])
            = *reinterpret_cast<uint4*>(o);
    }
}

// ------------------------------------------------------------------
// MFMA flash attention v10 = r8's proven body (max-free softmax,
// pair-tiled 64-row strips p & 15-p, 17 uniform steps) with the sync
// structure relaxed:
//  - K/V TRIPLE-buffered (s%3): stage(s+1) writes (s+1)%3 while the
//    slowest concurrent reader is compute(s-1) on (s-1)%3 -> the
//    trailing read-protection barrier is deleted. ONE barrier/step.
//  - per-wave vmcnt(4) + the single barrier still guarantee all
//    waves' stage(s) loads landed before compute(s).
//  - Ps stays wave-private (lgkm-only ordering, no barrier).
//  - T5 s_setprio(1) around QK and PV MFMA clusters.
// LDS 56KB -> 2 blocks/CU (grid 512 was already 2/CU: no occupancy
// cost, unlike r11's attempt).
// ------------------------------------------------------------------
__global__ __launch_bounds__(256) void attn_tb(
    const u16* __restrict__ qkv,  // [2048][3072]
    const u16* __restrict__ vT,   // [16*64][1024]
    u16* __restrict__ ob)         // [2048][2048]
{
    __shared__ u16 Ks[3][64 * 64];
    __shared__ u16 Vs[3][64 * 64];
    __shared__ u16 Ps[4][16 * 64];

    const int bid = blockIdx.x;
    const int L   = (bid & 7) * 64 + (bid >> 3);   // XCD-chunked, bijective
    const int g5  = L >> 5;                        // b*8 + kvh
    const int rem = L & 31;
    const int ha  = rem & 3;
    const int p   = rem >> 2;                      // pair index 0..7
    const int b = g5 >> 3, kvh = g5 & 7;
    const int h = kvh * 4 + ha;
    const int qtA = p, qtB = 15 - p;

    const int tid = threadIdx.x, w = tid >> 6, lane = tid & 63;
    const int l15 = lane & 15, lg = lane >> 4;
    const int srow = lane >> 3;
    const int scolsw = (lane & 7) ^ srow;

    // Q fragments for both tiles (q-row = l15 of wave's 16)
    bf16x8 qfA[2], qfB[2];
    {
        const size_t rA = (size_t)(b * 1024 + qtA * 64 + w * 16 + l15);
        const size_t rB = (size_t)(b * 1024 + qtB * 64 + w * 16 + l15);
        #pragma unroll
        for (int kk = 0; kk < 2; ++kk) {
            qfA[kk] = *reinterpret_cast<const bf16x8*>(
                &qkv[rA * 3072 + h * 64 + kk * 32 + lg * 8]);
            qfB[kk] = *reinterpret_cast<const bf16x8*>(
                &qkv[rB * 3072 + h * 64 + kk * 32 + lg * 8]);
        }
    }
    asm volatile("s_waitcnt vmcnt(0)" ::: "memory");  // clean vmcnt for pipeline

    float lrA = 0.f, lrB = 0.f;          // per-lane partial row sums
    f32x4 oaccA[4] = {}, oaccB[4] = {};

    const u16* kbase = qkv + 2048 + kvh * 64;
    const u16* vbase = vT + (size_t)(g5 * 64) * 1024;
    const int qgA = qtA * 64 + w * 16 + l15;
    const int qgB = qtB * 64 + w * 16 + l15;

#define ASTAGE(kt, bb) do {                                                    \
    _Pragma("unroll")                                                          \
    for (int i_ = 0; i_ < 2; ++i_) {                                           \
        int chunk_ = w * 2 + i_;                                               \
        int row_ = chunk_ * 8 + srow;                                          \
        gld_lds16(&kbase[(size_t)(b * 1024 + (kt) * 64 + row_) * 3072          \
                         + scolsw * 8], &Ks[bb][chunk_ * 512]);                \
        gld_lds16(&vbase[(size_t)row_ * 1024 + (kt) * 64 + scolsw * 8],        \
                  &Vs[bb][chunk_ * 512]);                                      \
    } } while (0)

    // one tile-step: max-free online accumulation (r8-verified body)
    auto step = [&](int kt, int cur, const bf16x8 (&qf)[2],
                    float& lr, f32x4 (&oacc)[4], int qg, bool dz) {
        // swapped QK^T: D[key][q], lane holds q=l15, keys m*16+lg*4+r
        f32x4 sacc[4] = {};
        __builtin_amdgcn_s_setprio(1);
        #pragma unroll
        for (int kk = 0; kk < 2; ++kk) {
            const int phys = ((kk * 4 + lg) ^ (l15 & 7)) * 8;
            #pragma unroll
            for (int m = 0; m < 4; ++m) {
                bf16x8 kf = *reinterpret_cast<const bf16x8*>(
                    &Ks[cur][(m * 16 + l15) * 64 + phys]);
                sacc[m] = __builtin_amdgcn_mfma_f32_16x16x32_bf16(
                    kf, qf[kk], sacc[m], 0, 0, 0);
            }
        }
        __builtin_amdgcn_s_setprio(0);

        // max-free: P = exp2(S * scale * log2e); masked -> exp2(-huge) = 0
        float ls = 0.f;
        #pragma unroll
        for (int m = 0; m < 4; ++m) {
            u16 pk[4];
            #pragma unroll
            for (int r = 0; r < 4; ++r) {
                float v = sacc[m][r] * 0.18033688f;   // 0.125 * log2(e)
                if (dz && (kt * 64 + m * 16 + lg * 4 + r > qg)) v = -1e30f;
                float e = exp2f(v);
                ls += e;
                pk[r] = f2bf(e);
            }
            const int keyc = m * 16 + lg * 4;
            const int phys = (keyc >> 3) ^ (l15 & 7);
            *reinterpret_cast<uint2*>(&Ps[w][l15 * 64 + phys * 8 + (keyc & 7)])
                = *reinterpret_cast<const uint2*>(pk);
        }
        lr += ls;                         // per-lane partial; reduce at end

        asm volatile("s_waitcnt lgkmcnt(0)" ::: "memory");  // Ps writes done
        __builtin_amdgcn_sched_barrier(0);

        // PV: O[q][d] += P[q][key] * V[key][d]
        __builtin_amdgcn_s_setprio(1);
        #pragma unroll
        for (int kk = 0; kk < 2; ++kk) {
            const int phys = ((kk * 4 + lg) ^ (l15 & 7)) * 8;
            bf16x8 pf = *reinterpret_cast<const bf16x8*>(
                &Ps[w][l15 * 64 + phys]);
            #pragma unroll
            for (int d = 0; d < 4; ++d) {
                bf16x8 vf = *reinterpret_cast<const bf16x8*>(
                    &Vs[cur][(d * 16 + l15) * 64 + phys]);
                oacc[d] = __builtin_amdgcn_mfma_f32_16x16x32_bf16(
                    pf, vf, oacc[d], 0, 0, 0);
            }
        }
        __builtin_amdgcn_s_setprio(0);
    };

    // 17-step schedule, ONE barrier per step (triple-buffered K/V):
    // s<=p -> tile A (kt=s), else tile B (kt=s-p-1)
    ASTAGE(0, 0);
    for (int s = 0; s <= 16; ++s) {
        const int cur = s % 3;
        if (s < 16) {
            const int ktn = (s + 1 <= p) ? (s + 1) : (s - p);
            ASTAGE(ktn, (s + 1) % 3);
            asm volatile("s_waitcnt vmcnt(4)" ::: "memory");
        } else {
            asm volatile("s_waitcnt vmcnt(0)" ::: "memory");
        }
        __builtin_amdgcn_sched_barrier(0);
        __builtin_amdgcn_s_barrier();
        __builtin_amdgcn_sched_barrier(0);

        if (s <= p) step(s,         cur, qfA, lrA, oaccA, qgA, s == p);
        else        step(s - p - 1, cur, qfB, lrB, oaccB, qgB, s == 16);
        // no trailing barrier: stage(s+1) at next iter writes (s+1)%3,
        // disjoint from any buffer still being read.
    }
#undef ASTAGE

    // epilogues: reduce l across the 4 lane-groups once, then normalize.
    #pragma unroll
    for (int tt = 0; tt < 2; ++tt) {
        const int qt = tt ? qtB : qtA;
        float lsum = tt ? lrB : lrA;
        lsum += __shfl_xor(lsum, 16);
        lsum += __shfl_xor(lsum, 32);
        f32x4* oacc = tt ? oaccB : oaccA;
        float linv[4];
        #pragma unroll
        for (int r = 0; r < 4; ++r) {
            float lv = __shfl(lsum, (lane & 48) + ((lane >> 4) & 3) * 4 + r);
            linv[r] = 1.f / lv;
        }
        #pragma unroll
        for (int d = 0; d < 4; ++d)
            #pragma unroll
            for (int r = 0; r < 4; ++r)
                ob[(size_t)(b * 1024 + qt * 64 + w * 16 + lg * 4 + r) * 2048
                   + h * 64 + d * 16 + l15] = f2bf(oacc[d][r] * linv[r]);
    }
}

// ------------------------------------------------------------------
extern "C" void kernel_launch(void* const* d_in, const int* in_sizes, int n_in,
                              void* d_out, int out_size, void* d_ws, size_t ws_size,
                              hipStream_t stream)
{
    const float* hidden = (const float*)d_in[0];
    const float* cosb   = (const float*)d_in[1];
    const float* sinb   = (const float*)d_in[2];
    // d_in[3] = attention_mask (pure causal; handled analytically)
    const float* wq     = (const float*)d_in[4];
    const float* wk     = (const float*)d_in[5];
    const float* wv     = (const float*)d_in[6];
    const float* wo     = (const float*)d_in[7];
    const float* qnw    = (const float*)d_in[8];
    const float* knw    = (const float*)d_in[9];
    float* out = (float*)d_out;

    char* ws = (char*)d_ws;
    u16* hidden_bf = (u16*)ws;                          // [0,8M)
    u16* wqkvT     = (u16*)(ws + ((size_t)8  << 20));   // [8,20M) -> later attn_bf
    u16* attn_bf   = (u16*)(ws + ((size_t)8  << 20));
    u16* qkv_bf    = (u16*)(ws + ((size_t)20 << 20));   // [20,32M)
    u16* v_bfT     = (u16*)(ws + ((size_t)32 << 20));   // [32,34M)
    u16* woT       = (u16*)(ws + ((size_t)34 << 20));   // [34,42M)

    // hidden -> bf16, wq|wk|wv pack-transpose, wo transpose
    preproc1<<<4608, 256, 0, stream>>>(hidden, wq, wk, wv, wo,
                                       hidden_bf, wqkvT, woT);

    // fused QKV projection: [2048,2048] @ [2048,3072] -> bf16 [2048,3072]
    gemm_bt<true><<<768, 256, 0, stream>>>(hidden_bf, wqkvT, qkv_bf,
                                           2048, 3072, 2048);

    // RMSNorm + RoPE for Q and K (in place) + V transpose
    rmsnorm_rope_vt<<<2304, 256, 0, stream>>>(qkv_bf, qnw, knw, cosb, sinb, v_bfT);

    // attention -> attn_bf (aliases wqkvT region, free after QKV GEMM)
    attn_tb<<<512, 256, 0, stream>>>(qkv_bf, v_bfT, attn_bf);

    // output projection: [2048,2048] @ woT^T -> fp32 out
    gemm_bt<false><<<512, 256, 0, stream>>>(attn_bf, woT, out,
                                            2048, 2048, 2048);
}